// Round 7
// baseline (284.857 us; speedup 1.0000x reference)
//
#include <hip/hip_runtime.h>
#include <stdint.h>

// ---------------------------------------------------------------------------
// HaloAttn: BLOCK=8, HALO=3, WIN=14, NH=8, DH=32, DIM=256, DV=256
// fp32 in/out; internal bf16 MFMA.
// R10: k_attn vT staging rewritten as quad-packed ds_write_b64 (layout
//      UNCHANGED -- R8 lesson): one pass, no divisions, pad loop folded in,
//      b64 writes at the wave64 bank minimum.  ~450 -> ~35 staging VALU.
//      k_qkv keeps R9's T3 double-buffer.  cvt_pk stays banned.
// ---------------------------------------------------------------------------

typedef short bf16s;                                      // raw bf16 storage
typedef bf16s bf16x8 __attribute__((ext_vector_type(8))); // MFMA A/B frag (K=32)
typedef bf16s bf16x4 __attribute__((ext_vector_type(4))); // MFMA A/B frag (K=16)
typedef float f32x4  __attribute__((ext_vector_type(4))); // MFMA C/D frag
typedef unsigned int u32x4 __attribute__((ext_vector_type(4)));

#define MFMA16(a, b, c) __builtin_amdgcn_mfma_f32_16x16x32_bf16(a, b, c, 0, 0, 0)
#define SCALE_QK 0.17677669529663687f
#define LOG2E 1.4426950408889634f
#define EXP_SHIFT 11.541560327111707f   // 8 * log2(e)
#define SCLOG 0.25503486142f            // SCALE_QK * LOG2E

// K=16 bf16 MFMA: prefer the carried-forward _1k builtin (gfx90a+ name).
__device__ __forceinline__ f32x4 pv_mfma(bf16x4 a, bf16x4 b, f32x4 c) {
#if __has_builtin(__builtin_amdgcn_mfma_f32_16x16x16bf16_1k)
  return __builtin_amdgcn_mfma_f32_16x16x16bf16_1k(a, b, c, 0, 0, 0);
#elif __has_builtin(__builtin_amdgcn_mfma_f32_16x16x16_bf16)
  return __builtin_amdgcn_mfma_f32_16x16x16_bf16(a, b, c, 0, 0, 0);
#else
  f32x4 d;
  asm volatile("v_mfma_f32_16x16x16_bf16 %0, %1, %2, %3\n\ts_nop 4\n\ts_nop 4"
               : "=v"(d) : "v"(a), "v"(b), "v"(c));
  return d;
#endif
}

__device__ __forceinline__ void async16(void* lds, const void* g) {
  __builtin_amdgcn_global_load_lds(
      (const __attribute__((address_space(1))) unsigned int*)g,
      (__attribute__((address_space(3))) unsigned int*)lds, 16, 0, 0);
}

__device__ __forceinline__ bf16s f2b(float f) {
  unsigned int u = __builtin_bit_cast(unsigned int, f);
  u = (u + 0x7fffu + ((u >> 16) & 1u)) >> 16;
  return (bf16s)u;
}

// ---------------------------------------------------------------------------
// K_convert: fp32 -> bf16 weights + rel tables ([relid][32r][32d], rows>=27=0)
// ---------------------------------------------------------------------------
__global__ __launch_bounds__(256) void k_convert(const float* __restrict__ wq,
                                                 const float* __restrict__ wkv,
                                                 const float* __restrict__ hrel,
                                                 const float* __restrict__ wrel,
                                                 bf16s* __restrict__ wq_b,
                                                 bf16s* __restrict__ wkv_b,
                                                 bf16s* __restrict__ rel_b) {
  int i = blockIdx.x * 256 + threadIdx.x;   // grid 776 * 256 = 198656 exact
  if (i < 65536) {
    wq_b[i] = f2b(wq[i]);
  } else if (i < 196608) {
    int j = i - 65536;
    wkv_b[j] = f2b(wkv[j]);
  } else {
    int r2 = i - 196608;                    // [0,2048)
    int relid = r2 >> 10, r = (r2 >> 5) & 31, d = r2 & 31;
    const float* src = relid ? hrel : wrel;
    rel_b[r2] = (r < 27) ? f2b(src[r * 32 + d]) : (bf16s)0;
  }
}

// ---------------------------------------------------------------------------
// K0: x fp32 (b,c,p) -> xT bf16 (b,p,c)
// ---------------------------------------------------------------------------
__global__ __launch_bounds__(256) void k_transpose(const float* __restrict__ x,
                                                   bf16s* __restrict__ xT) {
  __shared__ bf16s tile[64][72];
  const int ct = blockIdx.x, pt = blockIdx.y, b = blockIdx.z;
  const int t = threadIdx.x;
  const int r0 = t >> 3, c8 = (t & 7) * 8;
  const float* src = x + ((size_t)b * 256 + ct * 64) * 16384 + (size_t)pt * 64;
#pragma unroll
  for (int pass = 0; pass < 2; ++pass) {
    int r = pass * 32 + r0;
    const float4* sp = (const float4*)(src + (size_t)r * 16384 + c8);
    float4 f0 = sp[0], f1 = sp[1];
    bf16x8 v;
    v[0] = f2b(f0.x); v[1] = f2b(f0.y); v[2] = f2b(f0.z); v[3] = f2b(f0.w);
    v[4] = f2b(f1.x); v[5] = f2b(f1.y); v[6] = f2b(f1.z); v[7] = f2b(f1.w);
    *(bf16x8*)&tile[r][c8] = v;
  }
  __syncthreads();
  bf16s* dst = xT + ((size_t)b * 16384 + pt * 64) * 256 + ct * 64;
#pragma unroll
  for (int pass = 0; pass < 2; ++pass) {
    int p = pass * 32 + r0;
    bf16x8 v;
#pragma unroll
    for (int u = 0; u < 8; ++u) v[u] = tile[c8 + u][p];
    *(bf16x8*)(dst + (size_t)p * 256 + c8) = v;
  }
}

// ---------------------------------------------------------------------------
// K0b: zero the 3-pixel halo border of kv_ws [b][134][134][512]
// ---------------------------------------------------------------------------
__global__ __launch_bounds__(256) void k_zero_border(bf16s* __restrict__ kv) {
  const int gid = blockIdx.x * 256 + threadIdx.x;  // 4*1572*64 total
  const int chunk = gid & 63;
  const int rest = gid >> 6;
  const int b = rest / 1572, pxi = rest % 1572;
  int y, x;
  if (pxi < 804) {
    int r = pxi / 134;
    x = pxi % 134;
    y = (r < 3) ? r : 128 + r;
  } else {
    int p2 = pxi - 804;
    y = 3 + p2 / 6;
    int xi = p2 % 6;
    x = (xi < 3) ? xi : 128 + xi;
  }
  u32x4 z = {0, 0, 0, 0};
  *(u32x4*)(kv + (((size_t)b * 134 + y) * 134 + x) * 512 + chunk * 8) = z;
}

// ---------------------------------------------------------------------------
// K1: qkv projection GEMM.  T3 double-buffered staging (R9-proven).
// ---------------------------------------------------------------------------
__global__ __launch_bounds__(256) void k_qkv(const bf16s* __restrict__ wq,
                                             const bf16s* __restrict__ wkv,
                                             const bf16s* __restrict__ xT,
                                             bf16s* __restrict__ q_ws,
                                             bf16s* __restrict__ kv_ws) {
  __shared__ __align__(16) bf16s smem[17408];   // 34816 B
  const int mt = blockIdx.x, y = blockIdx.y, b = blockIdx.z;
  const int t = threadIdx.x;
  const int wv = t >> 6, lane = t & 63, g = lane >> 4, l15 = lane & 15;
  const int wm = wv & 1, wn = wv >> 1;
  const bf16s* Ag = (mt < 2) ? (wq + mt * 128 * 256) : (wkv + (mt - 2) * 128 * 256);
  const bf16s* Bg = xT + ((size_t)b * 16384 + y * 128) * 256;

  f32x4 acc[4][4];
#pragma unroll
  for (int i = 0; i < 4; ++i)
#pragma unroll
    for (int j = 0; j < 4; ++j) acc[i][j] = (f32x4){0.f, 0.f, 0.f, 0.f};

  const int s_row = ((unsigned)t) >> 2;          // slot row for hh=0
  const int s_k8 = (t & 3) * 8;
#define STAGE(kc_, cur_)                                                      \
  do {                                                                        \
    _Pragma("unroll")                                                         \
    for (int hh = 0; hh < 2; ++hh) {                                          \
      int row = hh * 64 + s_row;                                              \
      async16((char*)smem + (cur_)*16384 + hh * 4096 + wv * 1024,             \
              Ag + row * 256 + (kc_)*32 + s_k8);                              \
      async16((char*)smem + 8192 + (cur_)*16384 + hh * 4096 + wv * 1024,      \
              Bg + row * 256 + (kc_)*32 + s_k8);                              \
    }                                                                         \
  } while (0)

  STAGE(0, 0);
  __syncthreads();                // drains vmcnt -> buf0 ready
  int cur = 0;
#pragma unroll
  for (int kc = 0; kc < 8; ++kc) {
    if (kc < 7) STAGE(kc + 1, cur ^ 1);          // in flight under the MFMAs
    const bf16s* Alc = (const bf16s*)((char*)smem + cur * 16384);
    const bf16s* Blc = (const bf16s*)((char*)smem + 8192 + cur * 16384);
    bf16x8 af[4], bfr[4];
#pragma unroll
    for (int mi = 0; mi < 4; ++mi)
      af[mi] = *(const bf16x8*)&Alc[(wm * 64 + mi * 16 + l15) * 32 + g * 8];
#pragma unroll
    for (int ni = 0; ni < 4; ++ni)
      bfr[ni] = *(const bf16x8*)&Blc[(wn * 64 + ni * 16 + l15) * 32 + g * 8];
#pragma unroll
    for (int mi = 0; mi < 4; ++mi)
#pragma unroll
      for (int ni = 0; ni < 4; ++ni)
        acc[mi][ni] = MFMA16(af[mi], bfr[ni], acc[mi][ni]);
    __syncthreads();             // readers done + next stage drained
    cur ^= 1;
  }
#undef STAGE

  bf16s* Cl = smem;  // [px 128][o 128], stride 136
#pragma unroll
  for (int mi = 0; mi < 4; ++mi)
#pragma unroll
    for (int ni = 0; ni < 4; ++ni)
#pragma unroll
      for (int rg = 0; rg < 4; ++rg) {
        int m = wm * 64 + mi * 16 + g * 4 + rg;
        int n = wn * 64 + ni * 16 + l15;
        Cl[n * 136 + m] = f2b(acc[mi][ni][rg]);
      }
  __syncthreads();

  if (mt < 2) {
#pragma unroll
    for (int hh = 0; hh < 2; ++hh) {
      int rid = hh * 256 + t;
      int head = rid >> 7, bx = (rid >> 3) & 15, wc = rid & 7;
      int px = bx * 8 + wc;
      bf16s* dst = q_ws +
          ((((size_t)(b * 8 + mt * 4 + head) * 256 + (y >> 3) * 16 + bx) * 64 +
            (y & 7) * 8 + wc)) * 32;
#pragma unroll
      for (int c4 = 0; c4 < 4; ++c4)
        *(bf16x8*)(dst + c4 * 8) = *(const bf16x8*)&Cl[px * 136 + head * 32 + c4 * 8];
    }
  } else {
    int px = t >> 1, half = t & 1;
    bf16s* dst = kv_ws + (((size_t)b * 134 + y + 3) * 134 + px + 3) * 512 +
                 (mt - 2) * 128 + half * 64;
#pragma unroll
    for (int c8 = 0; c8 < 8; ++c8)
      *(bf16x8*)(dst + c8 * 8) = *(const bf16x8*)&Cl[px * 136 + half * 64 + c8 * 8];
  }
}

// ---------------------------------------------------------------------------
// K2: attention, S^T form.  One wg (4 waves) per (bh, block).
// Keys tiled column-major padded: key' = j*16 + i (j=0..13 -> 14 tiles,
// i=0..13 valid, 14..15 zero).  QK^T: acc[nt] lane (g,l15) =
// P^T[key nt*16+g*4+rg][q=l15].  PV uses 16x16x16 MFMA whose B-operand
// layout (k=g*4+j, col=l15) matches that C/D layout exactly -> P converts
// in-register (f2b), no cross-lane movement, no LDS P buffer.
// vT row stride 228 bf16: PV b64 reads conflict-free.  vT layout identical
// to R9; staging is quad-packed ds_write_b64 (one pass, no divisions,
// pads folded in, bank-minimum writes).
// LDS: vT 14592 + 4*4352 (per-wave RW/RH fp32) = 32000 -> 5 wg/CU
// ---------------------------------------------------------------------------
#define VSTRIDE 228
__global__ __launch_bounds__(256, 5) void k_attn(const bf16s* __restrict__ q_ws,
                                                 const bf16s* __restrict__ kv_ws,
                                                 const bf16s* __restrict__ rel_b,
                                                 float* __restrict__ outp) {
  __shared__ __align__(16) char arena[32000];
  bf16s* vT = (bf16s*)arena;                         // [d 32][key' VSTRIDE]
  const int t = threadIdx.x;
  const int wv = t >> 6, lane = t & 63, g = lane >> 4, l15 = lane & 15;
  char* pw = arena + 14592 + wv * 4352;              // per-wave private
  float* RWp = (float*)pw;                           // [16 q][34]
  float* RHp = RWp + 544;                            // [16 q][34]

  // XCD-aware swizzle: 4 adjacent bx per XCD slot for KV L2 reuse
  int wgid = blockIdx.x;
  int xcd = wgid & 7, chnk = wgid >> 3;
  int bxlo = chnk & 3, rest = chnk >> 2;
  int c = xcd * 256 + rest;               // 0..2047
  int bx = (c & 3) * 4 + bxlo;
  int byy = (c >> 2) & 15;
  int bh = c >> 6;                        // 0..31
  int b = bh >> 3, hd = bh & 7;
  int blk = byy * 16 + bx;

  const bf16s* kvb = kv_ws + (((size_t)b * 134 + byy * 8) * 134 + bx * 8) * 512 + hd * 64;
  const bf16s* qg  = q_ws + ((size_t)bh * 256 + blk) * 2048;

  // --- per-lane operand fragments straight from global (L2-hot) ---
  bf16x8 aq = *(const bf16x8*)(qg + (wv * 16 + l15) * 32 + g * 8);   // B: q
  const int i_cl = (l15 < 14) ? l15 : 13;
  const bf16s* kbase = kvb + (size_t)i_cl * 68608 + g * 8;           // 134*512
  bf16x8 kf[14];
#pragma unroll
  for (int nt = 0; nt < 14; ++nt)
    kf[nt] = *(const bf16x8*)(kbase + nt * 512);                     // A: k rows
  bf16x8 wf[2], hf[2];
#pragma unroll
  for (int t16 = 0; t16 < 2; ++t16) {
    wf[t16] = *(const bf16x8*)(rel_b + (t16 * 16 + l15) * 32 + g * 8);
    hf[t16] = *(const bf16x8*)(rel_b + 1024 + (t16 * 16 + l15) * 32 + g * 8);
  }

  // --- vT staging: quad-packed b64 writes, layout unchanged ---
  // thread t<224 owns (ch=t&3, i-quad iq=(t>>2)&3, j=t>>4): loads pixels
  // i0..i0+3 (i0=4*iq) of column j, channels ch*8..+7, writes 8 x b64 at
  // vT[d][j*16+i0].  iq==3 upper pair = pad slots 14/15 -> zeros (no load).
  if (t < 224) {
    const int ch = t & 3, iq = (t >> 2) & 3, j = t >> 4;   // j 0..13
    const int i0 = iq * 4;
    const bf16s* gp = kvb + (size_t)(i0 * 134 + j) * 512 + 32 + ch * 8;
    bf16x8 v0 = *(const bf16x8*)gp;
    bf16x8 v1 = *(const bf16x8*)(gp + 68608);
    bf16x8 v2 = {}, v3 = {};
    if (iq < 3) {
      v2 = *(const bf16x8*)(gp + 137216);
      v3 = *(const bf16x8*)(gp + 205824);
    }
    bf16s* wbase = vT + (ch * 8) * VSTRIDE + j * 16 + i0;
#pragma unroll
    for (int u = 0; u < 8; ++u) {
      unsigned int lo = (unsigned short)v0[u] |
                        ((unsigned int)(unsigned short)v1[u] << 16);
      unsigned int hi = (unsigned short)v2[u] |
                        ((unsigned int)(unsigned short)v3[u] << 16);
      *(uint2*)(wbase + u * VSTRIDE) = make_uint2(lo, hi);
    }
  }

  // --- QK^T (S^T): acc[nt] rows = keys nt*16+g*4+rg, col q ---
  f32x4 acc[14];
#pragma unroll
  for (int nt = 0; nt < 14; ++nt) acc[nt] = (f32x4){0.f, 0.f, 0.f, 0.f};
#pragma unroll
  for (int nt = 0; nt < 14; ++nt) acc[nt] = MFMA16(kf[nt], aq, acc[nt]);

  // --- rel logits: D[r][q] = q . rel[r]; fold LOG2E and -EXP_SHIFT here ---
  {
    f32x4 zz = (f32x4){0.f, 0.f, 0.f, 0.f};
#pragma unroll
    for (int t16 = 0; t16 < 2; ++t16) {
      f32x4 rw = MFMA16(wf[t16], aq, zz);
      f32x4 rh = MFMA16(hf[t16], aq, zz);
      float* wd = &RWp[l15 * 34 + t16 * 16 + g * 4];
      float* hd2 = &RHp[l15 * 34 + t16 * 16 + g * 4];
      *(float2*)wd       = make_float2(fmaf(rw[0], LOG2E, -EXP_SHIFT),
                                       fmaf(rw[1], LOG2E, -EXP_SHIFT));
      *(float2*)(wd + 2) = make_float2(fmaf(rw[2], LOG2E, -EXP_SHIFT),
                                       fmaf(rw[3], LOG2E, -EXP_SHIFT));
      *(float2*)hd2       = make_float2(rh[0] * LOG2E, rh[1] * LOG2E);
      *(float2*)(hd2 + 2) = make_float2(rh[2] * LOG2E, rh[3] * LOG2E);
    }
  }

  // --- softmax numerators (no normalize; fixed shift). jq=q&7, iq=q>>3 ---
  const int jq = l15 & 7;
  const int iqq = wv * 2 + (l15 >> 3);
  const float* RWr = RWp + l15 * 34;
  const float* RHr = RHp + l15 * 34;
  const int ihb = 13 + g * 4 - iqq;
  float h0 = RHr[ihb], h1 = RHr[ihb + 1], h2 = RHr[ihb + 2], h3 = RHr[ihb + 3];
  float sm = 0.f;
#pragma unroll
  for (int nt = 0; nt < 14; ++nt) {
    float w1 = RWr[13 + nt - jq];           // includes *LOG2E - EXP_SHIFT
    float e0 = exp2f(fmaf(acc[nt][0], SCLOG, w1 + h0));
    float e1 = exp2f(fmaf(acc[nt][1], SCLOG, w1 + h1));
    float e2 = exp2f(fmaf(acc[nt][2], SCLOG, w1 + h2));
    float e3 = exp2f(fmaf(acc[nt][3], SCLOG, w1 + h3));
    if (g == 3) { e2 = 0.f; e3 = 0.f; }   // key rows i=14,15 invalid
    sm += e0 + e1 + e2 + e3;
    acc[nt][0] = e0; acc[nt][1] = e1; acc[nt][2] = e2; acc[nt][3] = e3;
  }
  sm += __shfl_xor(sm, 16);
  sm += __shfl_xor(sm, 32);
  float rs = __builtin_amdgcn_rcpf(sm);

  __syncthreads();  // vT staged by all threads; P stays in registers

  // --- PV via 16x16x16 MFMA: O^T[d][q] = sum_nt Vt_nt * P_nt ---
  // B-frag: bpv[j] = P^T[key nt*16+g*4+j][q=l15] = acc[nt][j]  (layout match)
  // A-frag: a[j] = vT[d = l15 (+16)][key' = nt*16+g*4+j]
  f32x4 oa0 = (f32x4){0.f, 0.f, 0.f, 0.f};
  f32x4 oa1 = (f32x4){0.f, 0.f, 0.f, 0.f};
#pragma unroll
  for (int nt = 0; nt < 14; ++nt) {
    bf16x4 bpv;
    bpv[0] = f2b(acc[nt][0]); bpv[1] = f2b(acc[nt][1]);
    bpv[2] = f2b(acc[nt][2]); bpv[3] = f2b(acc[nt][3]);
    bf16x4 a0 = *(const bf16x4*)(vT + l15 * VSTRIDE + nt * 16 + g * 4);
    bf16x4 a1 = *(const bf16x4*)(vT + (16 + l15) * VSTRIDE + nt * 16 + g * 4);
    oa0 = pv_mfma(a0, bpv, oa0);
    oa1 = pv_mfma(a1, bpv, oa1);
  }

  // --- direct store: lane holds O[d = g*4+rg (+16)][q = wv*16+l15] ---
  {
    int py = wv * 2 + (l15 >> 3), px = l15 & 7;
    float* ob = outp + (((size_t)(b * 256 + hd * 32) * 128 + byy * 8 + py) * 128) +
                bx * 8 + px;
#pragma unroll
    for (int rg = 0; rg < 4; ++rg) {
      ob[(size_t)(g * 4 + rg) * 16384] = oa0[rg] * rs;
      ob[(size_t)(16 + g * 4 + rg) * 16384] = oa1[rg] * rs;
    }
  }
}

// ---------------------------------------------------------------------------
extern "C" void kernel_launch(void* const* d_in, const int* in_sizes, int n_in,
                              void* d_out, int out_size, void* d_ws, size_t ws_size,
                              hipStream_t stream) {
  (void)in_sizes; (void)n_in; (void)out_size; (void)ws_size;
  const float* x    = (const float*)d_in[0];
  const float* wq   = (const float*)d_in[1];
  const float* wkv  = (const float*)d_in[2];
  const float* hrel = (const float*)d_in[3];
  const float* wrel = (const float*)d_in[4];
  float* outp = (float*)d_out;

  bf16s* xT    = (bf16s*)d_ws;        // 16,777,216 elems
  bf16s* q_ws  = xT + 16777216;       // 16,777,216 elems
  bf16s* kv_ws = q_ws + 16777216;     // 36,773,888 elems
  bf16s* wq_b  = kv_ws + 36773888;    //     65,536
  bf16s* wkv_b = wq_b + 65536;        //    131,072
  bf16s* rel_b = wkv_b + 131072;      //      2,048

  hipLaunchKernelGGL(k_convert,    dim3(776),       dim3(256), 0, stream,
                     wq, wkv, hrel, wrel, wq_b, wkv_b, rel_b);
  hipLaunchKernelGGL(k_transpose,  dim3(4, 256, 4), dim3(256), 0, stream, x, xT);
  hipLaunchKernelGGL(k_zero_border, dim3(1572),     dim3(256), 0, stream, kv_ws);
  hipLaunchKernelGGL(k_qkv,        dim3(6, 128, 4), dim3(256), 0, stream,
                     wq_b, wkv_b, xT, q_ws, kv_ws);
  hipLaunchKernelGGL(k_attn,       dim3(8192),      dim3(256), 0, stream,
                     q_ws, kv_ws, rel_b, outp);
}

// Round 8
// 279.943 us; speedup vs baseline: 1.0176x; 1.0176x over previous
//
#include <hip/hip_runtime.h>
#include <stdint.h>

// ---------------------------------------------------------------------------
// HaloAttn: BLOCK=8, HALO=3, WIN=14, NH=8, DH=32, DIM=256, DV=256
// fp32 in/out; internal bf16 MFMA.
// R11: k_attn restored to R9-exact staging (89.7us proven; R8+R10 both show
//      any global-access reorder loses more in L2/HBM than VALU gains).
//      -inf h2/h3 masking replaces 28 cndmasks (no memory change).
//      convert+transpose+zero merged into ONE k_prep launch (5->3 kernels).
//      k_qkv keeps R9's T3 double-buffer.  cvt_pk stays banned.
// ---------------------------------------------------------------------------

typedef short bf16s;                                      // raw bf16 storage
typedef bf16s bf16x8 __attribute__((ext_vector_type(8))); // MFMA A/B frag (K=32)
typedef bf16s bf16x4 __attribute__((ext_vector_type(4))); // MFMA A/B frag (K=16)
typedef float f32x4  __attribute__((ext_vector_type(4))); // MFMA C/D frag
typedef unsigned int u32x4 __attribute__((ext_vector_type(4)));

#define MFMA16(a, b, c) __builtin_amdgcn_mfma_f32_16x16x32_bf16(a, b, c, 0, 0, 0)
#define SCALE_QK 0.17677669529663687f
#define LOG2E 1.4426950408889634f
#define EXP_SHIFT 11.541560327111707f   // 8 * log2(e)
#define SCLOG 0.25503486142f            // SCALE_QK * LOG2E

// K=16 bf16 MFMA: prefer the carried-forward _1k builtin (gfx90a+ name).
__device__ __forceinline__ f32x4 pv_mfma(bf16x4 a, bf16x4 b, f32x4 c) {
#if __has_builtin(__builtin_amdgcn_mfma_f32_16x16x16bf16_1k)
  return __builtin_amdgcn_mfma_f32_16x16x16bf16_1k(a, b, c, 0, 0, 0);
#elif __has_builtin(__builtin_amdgcn_mfma_f32_16x16x16_bf16)
  return __builtin_amdgcn_mfma_f32_16x16x16_bf16(a, b, c, 0, 0, 0);
#else
  f32x4 d;
  asm volatile("v_mfma_f32_16x16x16_bf16 %0, %1, %2, %3\n\ts_nop 4\n\ts_nop 4"
               : "=v"(d) : "v"(a), "v"(b), "v"(c));
  return d;
#endif
}

__device__ __forceinline__ void async16(void* lds, const void* g) {
  __builtin_amdgcn_global_load_lds(
      (const __attribute__((address_space(1))) unsigned int*)g,
      (__attribute__((address_space(3))) unsigned int*)lds, 16, 0, 0);
}

__device__ __forceinline__ bf16s f2b(float f) {
  unsigned int u = __builtin_bit_cast(unsigned int, f);
  u = (u + 0x7fffu + ((u >> 16) & 1u)) >> 16;
  return (bf16s)u;
}

// ---------------------------------------------------------------------------
// K_prep: merged {transpose | convert | zero_border}.  Each job's body and
// memory pattern is verbatim from the R9 kernels; only the launch merges.
//   blocks [0,4096)      : x fp32 (b,c,p) -> xT bf16 (b,p,c)
//   blocks [4096,4872)   : weight/rel fp32 -> bf16 conversion
//   blocks [4872,6444)   : zero the 3-px halo border of kv_ws
// ---------------------------------------------------------------------------
__global__ __launch_bounds__(256) void k_prep(const float* __restrict__ x,
                                              bf16s* __restrict__ xT,
                                              const float* __restrict__ wq,
                                              const float* __restrict__ wkv,
                                              const float* __restrict__ hrel,
                                              const float* __restrict__ wrel,
                                              bf16s* __restrict__ wq_b,
                                              bf16s* __restrict__ wkv_b,
                                              bf16s* __restrict__ rel_b,
                                              bf16s* __restrict__ kv) {
  __shared__ bf16s tile[64][72];
  const int bid = blockIdx.x;
  const int t = threadIdx.x;
  if (bid < 4096) {
    // --- transpose job (was dim3(4,256,4): ct + 4*pt + 1024*b) ---
    const int ct = bid & 3, pt = (bid >> 2) & 255, b = bid >> 10;
    const int r0 = t >> 3, c8 = (t & 7) * 8;
    const float* src = x + ((size_t)b * 256 + ct * 64) * 16384 + (size_t)pt * 64;
#pragma unroll
    for (int pass = 0; pass < 2; ++pass) {
      int r = pass * 32 + r0;
      const float4* sp = (const float4*)(src + (size_t)r * 16384 + c8);
      float4 f0 = sp[0], f1 = sp[1];
      bf16x8 v;
      v[0] = f2b(f0.x); v[1] = f2b(f0.y); v[2] = f2b(f0.z); v[3] = f2b(f0.w);
      v[4] = f2b(f1.x); v[5] = f2b(f1.y); v[6] = f2b(f1.z); v[7] = f2b(f1.w);
      *(bf16x8*)&tile[r][c8] = v;
    }
    __syncthreads();
    bf16s* dst = xT + ((size_t)b * 16384 + pt * 64) * 256 + ct * 64;
#pragma unroll
    for (int pass = 0; pass < 2; ++pass) {
      int p = pass * 32 + r0;
      bf16x8 v;
#pragma unroll
      for (int u = 0; u < 8; ++u) v[u] = tile[c8 + u][p];
      *(bf16x8*)(dst + (size_t)p * 256 + c8) = v;
    }
  } else if (bid < 4872) {
    // --- convert job (776 blocks, 198656 items exact) ---
    int i = (bid - 4096) * 256 + t;
    if (i < 65536) {
      wq_b[i] = f2b(wq[i]);
    } else if (i < 196608) {
      int j = i - 65536;
      wkv_b[j] = f2b(wkv[j]);
    } else {
      int r2 = i - 196608;                    // [0,2048)
      int relid = r2 >> 10, r = (r2 >> 5) & 31, d = r2 & 31;
      const float* src = relid ? hrel : wrel;
      rel_b[r2] = (r < 27) ? f2b(src[r * 32 + d]) : (bf16s)0;
    }
  } else {
    // --- zero-border job (1572 blocks) ---
    const int gid = (bid - 4872) * 256 + t;   // 4*1572*64 total
    const int chunk = gid & 63;
    const int rest = gid >> 6;
    const int b = rest / 1572, pxi = rest % 1572;
    int y, xx;
    if (pxi < 804) {
      int r = pxi / 134;
      xx = pxi % 134;
      y = (r < 3) ? r : 128 + r;
    } else {
      int p2 = pxi - 804;
      y = 3 + p2 / 6;
      int xi = p2 % 6;
      xx = (xi < 3) ? xi : 128 + xi;
    }
    u32x4 z = {0, 0, 0, 0};
    *(u32x4*)(kv + (((size_t)b * 134 + y) * 134 + xx) * 512 + chunk * 8) = z;
  }
}

// ---------------------------------------------------------------------------
// K1: qkv projection GEMM.  T3 double-buffered staging (R9-proven).
// ---------------------------------------------------------------------------
__global__ __launch_bounds__(256) void k_qkv(const bf16s* __restrict__ wq,
                                             const bf16s* __restrict__ wkv,
                                             const bf16s* __restrict__ xT,
                                             bf16s* __restrict__ q_ws,
                                             bf16s* __restrict__ kv_ws) {
  __shared__ __align__(16) bf16s smem[17408];   // 34816 B
  const int mt = blockIdx.x, y = blockIdx.y, b = blockIdx.z;
  const int t = threadIdx.x;
  const int wv = t >> 6, lane = t & 63, g = lane >> 4, l15 = lane & 15;
  const int wm = wv & 1, wn = wv >> 1;
  const bf16s* Ag = (mt < 2) ? (wq + mt * 128 * 256) : (wkv + (mt - 2) * 128 * 256);
  const bf16s* Bg = xT + ((size_t)b * 16384 + y * 128) * 256;

  f32x4 acc[4][4];
#pragma unroll
  for (int i = 0; i < 4; ++i)
#pragma unroll
    for (int j = 0; j < 4; ++j) acc[i][j] = (f32x4){0.f, 0.f, 0.f, 0.f};

  const int s_row = ((unsigned)t) >> 2;          // slot row for hh=0
  const int s_k8 = (t & 3) * 8;
#define STAGE(kc_, cur_)                                                      \
  do {                                                                        \
    _Pragma("unroll")                                                         \
    for (int hh = 0; hh < 2; ++hh) {                                          \
      int row = hh * 64 + s_row;                                              \
      async16((char*)smem + (cur_)*16384 + hh * 4096 + wv * 1024,             \
              Ag + row * 256 + (kc_)*32 + s_k8);                              \
      async16((char*)smem + 8192 + (cur_)*16384 + hh * 4096 + wv * 1024,      \
              Bg + row * 256 + (kc_)*32 + s_k8);                              \
    }                                                                         \
  } while (0)

  STAGE(0, 0);
  __syncthreads();                // drains vmcnt -> buf0 ready
  int cur = 0;
#pragma unroll
  for (int kc = 0; kc < 8; ++kc) {
    if (kc < 7) STAGE(kc + 1, cur ^ 1);          // in flight under the MFMAs
    const bf16s* Alc = (const bf16s*)((char*)smem + cur * 16384);
    const bf16s* Blc = (const bf16s*)((char*)smem + 8192 + cur * 16384);
    bf16x8 af[4], bfr[4];
#pragma unroll
    for (int mi = 0; mi < 4; ++mi)
      af[mi] = *(const bf16x8*)&Alc[(wm * 64 + mi * 16 + l15) * 32 + g * 8];
#pragma unroll
    for (int ni = 0; ni < 4; ++ni)
      bfr[ni] = *(const bf16x8*)&Blc[(wn * 64 + ni * 16 + l15) * 32 + g * 8];
#pragma unroll
    for (int mi = 0; mi < 4; ++mi)
#pragma unroll
      for (int ni = 0; ni < 4; ++ni)
        acc[mi][ni] = MFMA16(af[mi], bfr[ni], acc[mi][ni]);
    __syncthreads();             // readers done + next stage drained
    cur ^= 1;
  }
#undef STAGE

  bf16s* Cl = smem;  // [px 128][o 128], stride 136
#pragma unroll
  for (int mi = 0; mi < 4; ++mi)
#pragma unroll
    for (int ni = 0; ni < 4; ++ni)
#pragma unroll
      for (int rg = 0; rg < 4; ++rg) {
        int m = wm * 64 + mi * 16 + g * 4 + rg;
        int n = wn * 64 + ni * 16 + l15;
        Cl[n * 136 + m] = f2b(acc[mi][ni][rg]);
      }
  __syncthreads();

  if (mt < 2) {
#pragma unroll
    for (int hh = 0; hh < 2; ++hh) {
      int rid = hh * 256 + t;
      int head = rid >> 7, bx = (rid >> 3) & 15, wc = rid & 7;
      int px = bx * 8 + wc;
      bf16s* dst = q_ws +
          ((((size_t)(b * 8 + mt * 4 + head) * 256 + (y >> 3) * 16 + bx) * 64 +
            (y & 7) * 8 + wc)) * 32;
#pragma unroll
      for (int c4 = 0; c4 < 4; ++c4)
        *(bf16x8*)(dst + c4 * 8) = *(const bf16x8*)&Cl[px * 136 + head * 32 + c4 * 8];
    }
  } else {
    int px = t >> 1, half = t & 1;
    bf16s* dst = kv_ws + (((size_t)b * 134 + y + 3) * 134 + px + 3) * 512 +
                 (mt - 2) * 128 + half * 64;
#pragma unroll
    for (int c8 = 0; c8 < 8; ++c8)
      *(bf16x8*)(dst + c8 * 8) = *(const bf16x8*)&Cl[px * 136 + half * 64 + c8 * 8];
  }
}

// ---------------------------------------------------------------------------
// K2: attention, S^T form (R9-exact memory patterns).  One wg per (bh,block).
// Keys tiled column-major padded: key' = j*16 + i (j=0..13 -> 14 tiles,
// i=0..13 valid, 14..15 zero).  QK^T: acc[nt] lane (g,l15) =
// P^T[key nt*16+g*4+rg][q=l15].  PV uses 16x16x16 MFMA whose B-operand
// layout (k=g*4+j, col=l15) matches that C/D layout exactly -> P converts
// in-register (f2b), no cross-lane movement, no LDS P buffer.
// vT row stride 228 bf16: PV b64 reads conflict-free.
// g==3 key rows 14/15 masked via h2/h3 = -inf (exp2 -> exact 0, no cndmask).
// LDS: vT 14592 + 4*4352 (per-wave RW/RH fp32) = 32000 -> 5 wg/CU
// ---------------------------------------------------------------------------
#define VSTRIDE 228
__global__ __launch_bounds__(256, 5) void k_attn(const bf16s* __restrict__ q_ws,
                                                 const bf16s* __restrict__ kv_ws,
                                                 const bf16s* __restrict__ rel_b,
                                                 float* __restrict__ outp) {
  __shared__ __align__(16) char arena[32000];
  bf16s* vT = (bf16s*)arena;                         // [d 32][key' VSTRIDE]
  const int t = threadIdx.x;
  const int wv = t >> 6, lane = t & 63, g = lane >> 4, l15 = lane & 15;
  char* pw = arena + 14592 + wv * 4352;              // per-wave private
  float* RWp = (float*)pw;                           // [16 q][34]
  float* RHp = RWp + 544;                            // [16 q][34]

  // XCD-aware swizzle: 4 adjacent bx per XCD slot for KV L2 reuse
  int wgid = blockIdx.x;
  int xcd = wgid & 7, chnk = wgid >> 3;
  int bxlo = chnk & 3, rest = chnk >> 2;
  int c = xcd * 256 + rest;               // 0..2047
  int bx = (c & 3) * 4 + bxlo;
  int byy = (c >> 2) & 15;
  int bh = c >> 6;                        // 0..31
  int b = bh >> 3, hd = bh & 7;
  int blk = byy * 16 + bx;

  const bf16s* kvb = kv_ws + (((size_t)b * 134 + byy * 8) * 134 + bx * 8) * 512 + hd * 64;
  const bf16s* qg  = q_ws + ((size_t)bh * 256 + blk) * 2048;

  // --- per-lane operand fragments straight from global (L2-hot) ---
  bf16x8 aq = *(const bf16x8*)(qg + (wv * 16 + l15) * 32 + g * 8);   // B: q
  const int i_cl = (l15 < 14) ? l15 : 13;
  const bf16s* kbase = kvb + (size_t)i_cl * 68608 + g * 8;           // 134*512
  bf16x8 kf[14];
#pragma unroll
  for (int nt = 0; nt < 14; ++nt)
    kf[nt] = *(const bf16x8*)(kbase + nt * 512);                     // A: k rows
  bf16x8 wf[2], hf[2];
#pragma unroll
  for (int t16 = 0; t16 < 2; ++t16) {
    wf[t16] = *(const bf16x8*)(rel_b + (t16 * 16 + l15) * 32 + g * 8);
    hf[t16] = *(const bf16x8*)(rel_b + 1024 + (t16 * 16 + l15) * 32 + g * 8);
  }

  // --- cooperative vT staging: vT[d][j*16+i] = v[pixel(i,j)][d] ---
  for (int idx = t; idx < 784; idx += 256) {
    int pos = idx >> 2, ch = idx & 3;
    int i = pos / 14, j = pos - i * 14;
    bf16x8 v = *(const bf16x8*)(kvb + (size_t)(i * 134 + j) * 512 + 32 + ch * 8);
#pragma unroll
    for (int u = 0; u < 8; ++u) vT[(ch * 8 + u) * VSTRIDE + j * 16 + i] = v[u];
  }
  for (int idx = t; idx < 896; idx += 256) {  // zero pad cols i=14,15
    int d = idx / 28, r = idx - d * 28;
    vT[d * VSTRIDE + (r >> 1) * 16 + 14 + (r & 1)] = 0;
  }

  // --- QK^T (S^T): acc[nt] rows = keys nt*16+g*4+rg, col q ---
  f32x4 acc[14];
#pragma unroll
  for (int nt = 0; nt < 14; ++nt) acc[nt] = (f32x4){0.f, 0.f, 0.f, 0.f};
#pragma unroll
  for (int nt = 0; nt < 14; ++nt) acc[nt] = MFMA16(kf[nt], aq, acc[nt]);

  // --- rel logits: D[r][q] = q . rel[r]; fold LOG2E and -EXP_SHIFT here ---
  {
    f32x4 zz = (f32x4){0.f, 0.f, 0.f, 0.f};
#pragma unroll
    for (int t16 = 0; t16 < 2; ++t16) {
      f32x4 rw = MFMA16(wf[t16], aq, zz);
      f32x4 rh = MFMA16(hf[t16], aq, zz);
      float* wd = &RWp[l15 * 34 + t16 * 16 + g * 4];
      float* hd2 = &RHp[l15 * 34 + t16 * 16 + g * 4];
      *(float2*)wd       = make_float2(fmaf(rw[0], LOG2E, -EXP_SHIFT),
                                       fmaf(rw[1], LOG2E, -EXP_SHIFT));
      *(float2*)(wd + 2) = make_float2(fmaf(rw[2], LOG2E, -EXP_SHIFT),
                                       fmaf(rw[3], LOG2E, -EXP_SHIFT));
      *(float2*)hd2       = make_float2(rh[0] * LOG2E, rh[1] * LOG2E);
      *(float2*)(hd2 + 2) = make_float2(rh[2] * LOG2E, rh[3] * LOG2E);
    }
  }

  // --- softmax numerators (no normalize; fixed shift). jq=q&7, iq=q>>3 ---
  const int jq = l15 & 7;
  const int iq = wv * 2 + (l15 >> 3);
  const float* RWr = RWp + l15 * 34;
  const float* RHr = RHp + l15 * 34;
  const int ihb = 13 + g * 4 - iq;
  const float NINF = -__builtin_inff();
  float h0 = RHr[ihb], h1 = RHr[ihb + 1];
  float h2 = (g == 3) ? NINF : RHr[ihb + 2];   // key rows 14/15 -> exp2 = 0
  float h3 = (g == 3) ? NINF : RHr[ihb + 3];
  float sm = 0.f;
#pragma unroll
  for (int nt = 0; nt < 14; ++nt) {
    float w1 = RWr[13 + nt - jq];           // includes *LOG2E - EXP_SHIFT
    float e0 = exp2f(fmaf(acc[nt][0], SCLOG, w1 + h0));
    float e1 = exp2f(fmaf(acc[nt][1], SCLOG, w1 + h1));
    float e2 = exp2f(fmaf(acc[nt][2], SCLOG, w1 + h2));
    float e3 = exp2f(fmaf(acc[nt][3], SCLOG, w1 + h3));
    sm += e0 + e1 + e2 + e3;
    acc[nt][0] = e0; acc[nt][1] = e1; acc[nt][2] = e2; acc[nt][3] = e3;
  }
  sm += __shfl_xor(sm, 16);
  sm += __shfl_xor(sm, 32);
  float rs = __builtin_amdgcn_rcpf(sm);

  __syncthreads();  // vT staged by all threads; P stays in registers

  // --- PV via 16x16x16 MFMA: O^T[d][q] = sum_nt Vt_nt * P_nt ---
  // B-frag: bpv[j] = P^T[key nt*16+g*4+j][q=l15] = acc[nt][j]  (layout match)
  // A-frag: a[j] = vT[d = l15 (+16)][key' = nt*16+g*4+j]
  f32x4 oa0 = (f32x4){0.f, 0.f, 0.f, 0.f};
  f32x4 oa1 = (f32x4){0.f, 0.f, 0.f, 0.f};
#pragma unroll
  for (int nt = 0; nt < 14; ++nt) {
    bf16x4 bpv;
    bpv[0] = f2b(acc[nt][0]); bpv[1] = f2b(acc[nt][1]);
    bpv[2] = f2b(acc[nt][2]); bpv[3] = f2b(acc[nt][3]);
    bf16x4 a0 = *(const bf16x4*)(vT + l15 * VSTRIDE + nt * 16 + g * 4);
    bf16x4 a1 = *(const bf16x4*)(vT + (16 + l15) * VSTRIDE + nt * 16 + g * 4);
    oa0 = pv_mfma(a0, bpv, oa0);
    oa1 = pv_mfma(a1, bpv, oa1);
  }

  // --- direct store: lane holds O[d = g*4+rg (+16)][q = wv*16+l15] ---
  {
    int py = wv * 2 + (l15 >> 3), px = l15 & 7;
    float* ob = outp + (((size_t)(b * 256 + hd * 32) * 128 + byy * 8 + py) * 128) +
                bx * 8 + px;
#pragma unroll
    for (int rg = 0; rg < 4; ++rg) {
      ob[(size_t)(g * 4 + rg) * 16384] = oa0[rg] * rs;
      ob[(size_t)(16 + g * 4 + rg) * 16384] = oa1[rg] * rs;
    }
  }
}

// ---------------------------------------------------------------------------
extern "C" void kernel_launch(void* const* d_in, const int* in_sizes, int n_in,
                              void* d_out, int out_size, void* d_ws, size_t ws_size,
                              hipStream_t stream) {
  (void)in_sizes; (void)n_in; (void)out_size; (void)ws_size;
  const float* x    = (const float*)d_in[0];
  const float* wq   = (const float*)d_in[1];
  const float* wkv  = (const float*)d_in[2];
  const float* hrel = (const float*)d_in[3];
  const float* wrel = (const float*)d_in[4];
  float* outp = (float*)d_out;

  bf16s* xT    = (bf16s*)d_ws;        // 16,777,216 elems
  bf16s* q_ws  = xT + 16777216;       // 16,777,216 elems
  bf16s* kv_ws = q_ws + 16777216;     // 36,773,888 elems
  bf16s* wq_b  = kv_ws + 36773888;    //     65,536
  bf16s* wkv_b = wq_b + 65536;        //    131,072
  bf16s* rel_b = wkv_b + 131072;      //      2,048

  hipLaunchKernelGGL(k_prep, dim3(6444), dim3(256), 0, stream,
                     x, xT, wq, wkv, hrel, wrel, wq_b, wkv_b, rel_b, kv_ws);
  hipLaunchKernelGGL(k_qkv,  dim3(6, 128, 4), dim3(256), 0, stream,
                     wq_b, wkv_b, xT, q_ws, kv_ws);
  hipLaunchKernelGGL(k_attn, dim3(8192),      dim3(256), 0, stream,
                     q_ws, kv_ws, rel_b, outp);
}

// Round 9
// 268.502 us; speedup vs baseline: 1.0609x; 1.0426x over previous
//
#include <hip/hip_runtime.h>
#include <stdint.h>

// ---------------------------------------------------------------------------
// HaloAttn: BLOCK=8, HALO=3, WIN=14, NH=8, DH=32, DIM=256, DV=256
// fp32 in/out; internal bf16 MFMA.
// R12: everything = R9-exact (best: 273.9us) EXCEPT k_qkv gets an XCD-aware
//      grid swizzle: all 6 mt-blocks sharing one xT tile land on the SAME
//      XCD (adjacent in its queue) -> xT fetched once per XCD instead of 6x.
//      Pure index remap; no layout/sync/loop changes.  cvt_pk stays banned.
// ---------------------------------------------------------------------------

typedef short bf16s;                                      // raw bf16 storage
typedef bf16s bf16x8 __attribute__((ext_vector_type(8))); // MFMA A/B frag (K=32)
typedef bf16s bf16x4 __attribute__((ext_vector_type(4))); // MFMA A/B frag (K=16)
typedef float f32x4  __attribute__((ext_vector_type(4))); // MFMA C/D frag
typedef unsigned int u32x4 __attribute__((ext_vector_type(4)));

#define MFMA16(a, b, c) __builtin_amdgcn_mfma_f32_16x16x32_bf16(a, b, c, 0, 0, 0)
#define SCALE_QK 0.17677669529663687f
#define LOG2E 1.4426950408889634f
#define EXP_SHIFT 11.541560327111707f   // 8 * log2(e)
#define SCLOG 0.25503486142f            // SCALE_QK * LOG2E

// K=16 bf16 MFMA: prefer the carried-forward _1k builtin (gfx90a+ name).
__device__ __forceinline__ f32x4 pv_mfma(bf16x4 a, bf16x4 b, f32x4 c) {
#if __has_builtin(__builtin_amdgcn_mfma_f32_16x16x16bf16_1k)
  return __builtin_amdgcn_mfma_f32_16x16x16bf16_1k(a, b, c, 0, 0, 0);
#elif __has_builtin(__builtin_amdgcn_mfma_f32_16x16x16_bf16)
  return __builtin_amdgcn_mfma_f32_16x16x16_bf16(a, b, c, 0, 0, 0);
#else
  f32x4 d;
  asm volatile("v_mfma_f32_16x16x16_bf16 %0, %1, %2, %3\n\ts_nop 4\n\ts_nop 4"
               : "=v"(d) : "v"(a), "v"(b), "v"(c));
  return d;
#endif
}

__device__ __forceinline__ void async16(void* lds, const void* g) {
  __builtin_amdgcn_global_load_lds(
      (const __attribute__((address_space(1))) unsigned int*)g,
      (__attribute__((address_space(3))) unsigned int*)lds, 16, 0, 0);
}

__device__ __forceinline__ bf16s f2b(float f) {
  unsigned int u = __builtin_bit_cast(unsigned int, f);
  u = (u + 0x7fffu + ((u >> 16) & 1u)) >> 16;
  return (bf16s)u;
}

// ---------------------------------------------------------------------------
// K_convert: fp32 -> bf16 weights + rel tables ([relid][32r][32d], rows>=27=0)
// ---------------------------------------------------------------------------
__global__ __launch_bounds__(256) void k_convert(const float* __restrict__ wq,
                                                 const float* __restrict__ wkv,
                                                 const float* __restrict__ hrel,
                                                 const float* __restrict__ wrel,
                                                 bf16s* __restrict__ wq_b,
                                                 bf16s* __restrict__ wkv_b,
                                                 bf16s* __restrict__ rel_b) {
  int i = blockIdx.x * 256 + threadIdx.x;   // grid 776 * 256 = 198656 exact
  if (i < 65536) {
    wq_b[i] = f2b(wq[i]);
  } else if (i < 196608) {
    int j = i - 65536;
    wkv_b[j] = f2b(wkv[j]);
  } else {
    int r2 = i - 196608;                    // [0,2048)
    int relid = r2 >> 10, r = (r2 >> 5) & 31, d = r2 & 31;
    const float* src = relid ? hrel : wrel;
    rel_b[r2] = (r < 27) ? f2b(src[r * 32 + d]) : (bf16s)0;
  }
}

// ---------------------------------------------------------------------------
// K0: x fp32 (b,c,p) -> xT bf16 (b,p,c)
// ---------------------------------------------------------------------------
__global__ __launch_bounds__(256) void k_transpose(const float* __restrict__ x,
                                                   bf16s* __restrict__ xT) {
  __shared__ bf16s tile[64][72];
  const int ct = blockIdx.x, pt = blockIdx.y, b = blockIdx.z;
  const int t = threadIdx.x;
  const int r0 = t >> 3, c8 = (t & 7) * 8;
  const float* src = x + ((size_t)b * 256 + ct * 64) * 16384 + (size_t)pt * 64;
#pragma unroll
  for (int pass = 0; pass < 2; ++pass) {
    int r = pass * 32 + r0;
    const float4* sp = (const float4*)(src + (size_t)r * 16384 + c8);
    float4 f0 = sp[0], f1 = sp[1];
    bf16x8 v;
    v[0] = f2b(f0.x); v[1] = f2b(f0.y); v[2] = f2b(f0.z); v[3] = f2b(f0.w);
    v[4] = f2b(f1.x); v[5] = f2b(f1.y); v[6] = f2b(f1.z); v[7] = f2b(f1.w);
    *(bf16x8*)&tile[r][c8] = v;
  }
  __syncthreads();
  bf16s* dst = xT + ((size_t)b * 16384 + pt * 64) * 256 + ct * 64;
#pragma unroll
  for (int pass = 0; pass < 2; ++pass) {
    int p = pass * 32 + r0;
    bf16x8 v;
#pragma unroll
    for (int u = 0; u < 8; ++u) v[u] = tile[c8 + u][p];
    *(bf16x8*)(dst + (size_t)p * 256 + c8) = v;
  }
}

// ---------------------------------------------------------------------------
// K0b: zero the 3-pixel halo border of kv_ws [b][134][134][512]
// ---------------------------------------------------------------------------
__global__ __launch_bounds__(256) void k_zero_border(bf16s* __restrict__ kv) {
  const int gid = blockIdx.x * 256 + threadIdx.x;  // 4*1572*64 total
  const int chunk = gid & 63;
  const int rest = gid >> 6;
  const int b = rest / 1572, pxi = rest % 1572;
  int y, x;
  if (pxi < 804) {
    int r = pxi / 134;
    x = pxi % 134;
    y = (r < 3) ? r : 128 + r;
  } else {
    int p2 = pxi - 804;
    y = 3 + p2 / 6;
    int xi = p2 % 6;
    x = (xi < 3) ? xi : 128 + xi;
  }
  u32x4 z = {0, 0, 0, 0};
  *(u32x4*)(kv + (((size_t)b * 134 + y) * 134 + x) * 512 + chunk * 8) = z;
}

// ---------------------------------------------------------------------------
// K1: qkv projection GEMM.  T3 double-buffered staging (R9-proven) +
// R12 XCD swizzle: linear grid 3072; xcd = wgid&7, i = wgid>>3, mt = i%6,
// pair p = xcd*64 + i/6, y = p>>2, b = p&3.  The 6 mt-blocks of a pair are
// wgid = ((p%64)*6+mt)*8 + p/64 -> same XCD, adjacent -> xT tile L2-hot.
// ---------------------------------------------------------------------------
__global__ __launch_bounds__(256) void k_qkv(const bf16s* __restrict__ wq,
                                             const bf16s* __restrict__ wkv,
                                             const bf16s* __restrict__ xT,
                                             bf16s* __restrict__ q_ws,
                                             bf16s* __restrict__ kv_ws) {
  __shared__ __align__(16) bf16s smem[17408];   // 34816 B
  const int wgid = blockIdx.x;
  const int xcd = wgid & 7, ii = wgid >> 3;
  const int mt = ii % 6;
  const int p = xcd * 64 + ii / 6;
  const int y = p >> 2, b = p & 3;
  const int t = threadIdx.x;
  const int wv = t >> 6, lane = t & 63, g = lane >> 4, l15 = lane & 15;
  const int wm = wv & 1, wn = wv >> 1;
  const bf16s* Ag = (mt < 2) ? (wq + mt * 128 * 256) : (wkv + (mt - 2) * 128 * 256);
  const bf16s* Bg = xT + ((size_t)b * 16384 + y * 128) * 256;

  f32x4 acc[4][4];
#pragma unroll
  for (int i = 0; i < 4; ++i)
#pragma unroll
    for (int j = 0; j < 4; ++j) acc[i][j] = (f32x4){0.f, 0.f, 0.f, 0.f};

  const int s_row = ((unsigned)t) >> 2;          // slot row for hh=0
  const int s_k8 = (t & 3) * 8;
#define STAGE(kc_, cur_)                                                      \
  do {                                                                        \
    _Pragma("unroll")                                                         \
    for (int hh = 0; hh < 2; ++hh) {                                          \
      int row = hh * 64 + s_row;                                              \
      async16((char*)smem + (cur_)*16384 + hh * 4096 + wv * 1024,             \
              Ag + row * 256 + (kc_)*32 + s_k8);                              \
      async16((char*)smem + 8192 + (cur_)*16384 + hh * 4096 + wv * 1024,      \
              Bg + row * 256 + (kc_)*32 + s_k8);                              \
    }                                                                         \
  } while (0)

  STAGE(0, 0);
  __syncthreads();                // drains vmcnt -> buf0 ready
  int cur = 0;
#pragma unroll
  for (int kc = 0; kc < 8; ++kc) {
    if (kc < 7) STAGE(kc + 1, cur ^ 1);          // in flight under the MFMAs
    const bf16s* Alc = (const bf16s*)((char*)smem + cur * 16384);
    const bf16s* Blc = (const bf16s*)((char*)smem + 8192 + cur * 16384);
    bf16x8 af[4], bfr[4];
#pragma unroll
    for (int mi = 0; mi < 4; ++mi)
      af[mi] = *(const bf16x8*)&Alc[(wm * 64 + mi * 16 + l15) * 32 + g * 8];
#pragma unroll
    for (int ni = 0; ni < 4; ++ni)
      bfr[ni] = *(const bf16x8*)&Blc[(wn * 64 + ni * 16 + l15) * 32 + g * 8];
#pragma unroll
    for (int mi = 0; mi < 4; ++mi)
#pragma unroll
      for (int ni = 0; ni < 4; ++ni)
        acc[mi][ni] = MFMA16(af[mi], bfr[ni], acc[mi][ni]);
    __syncthreads();             // readers done + next stage drained
    cur ^= 1;
  }
#undef STAGE

  bf16s* Cl = smem;  // [px 128][o 128], stride 136
#pragma unroll
  for (int mi = 0; mi < 4; ++mi)
#pragma unroll
    for (int ni = 0; ni < 4; ++ni)
#pragma unroll
      for (int rg = 0; rg < 4; ++rg) {
        int m = wm * 64 + mi * 16 + g * 4 + rg;
        int n = wn * 64 + ni * 16 + l15;
        Cl[n * 136 + m] = f2b(acc[mi][ni][rg]);
      }
  __syncthreads();

  if (mt < 2) {
#pragma unroll
    for (int hh = 0; hh < 2; ++hh) {
      int rid = hh * 256 + t;
      int head = rid >> 7, bx = (rid >> 3) & 15, wc = rid & 7;
      int px = bx * 8 + wc;
      bf16s* dst = q_ws +
          ((((size_t)(b * 8 + mt * 4 + head) * 256 + (y >> 3) * 16 + bx) * 64 +
            (y & 7) * 8 + wc)) * 32;
#pragma unroll
      for (int c4 = 0; c4 < 4; ++c4)
        *(bf16x8*)(dst + c4 * 8) = *(const bf16x8*)&Cl[px * 136 + head * 32 + c4 * 8];
    }
  } else {
    int px = t >> 1, half = t & 1;
    bf16s* dst = kv_ws + (((size_t)b * 134 + y + 3) * 134 + px + 3) * 512 +
                 (mt - 2) * 128 + half * 64;
#pragma unroll
    for (int c8 = 0; c8 < 8; ++c8)
      *(bf16x8*)(dst + c8 * 8) = *(const bf16x8*)&Cl[px * 136 + half * 64 + c8 * 8];
  }
}

// ---------------------------------------------------------------------------
// K2: attention, S^T form (R9-exact, 89.7us proven).  One wg per (bh,block).
// Keys tiled column-major padded: key' = j*16 + i (j=0..13 -> 14 tiles,
// i=0..13 valid, 14..15 masked).  QK^T: acc[nt] lane (g,l15) =
// P^T[key nt*16+g*4+rg][q=l15].  PV uses 16x16x16 MFMA whose B-operand
// layout (k=g*4+j, col=l15) matches that C/D layout exactly -> P converts
// in-register (f2b), no cross-lane movement, no LDS P buffer.
// vT row stride 228 bf16: PV b64 reads conflict-free.
// LDS: vT 14592 + 4*4352 (per-wave RW/RH fp32) = 32000 -> 5 wg/CU
// ---------------------------------------------------------------------------
#define VSTRIDE 228
__global__ __launch_bounds__(256, 5) void k_attn(const bf16s* __restrict__ q_ws,
                                                 const bf16s* __restrict__ kv_ws,
                                                 const bf16s* __restrict__ rel_b,
                                                 float* __restrict__ outp) {
  __shared__ __align__(16) char arena[32000];
  bf16s* vT = (bf16s*)arena;                         // [d 32][key' VSTRIDE]
  const int t = threadIdx.x;
  const int wv = t >> 6, lane = t & 63, g = lane >> 4, l15 = lane & 15;
  char* pw = arena + 14592 + wv * 4352;              // per-wave private
  float* RWp = (float*)pw;                           // [16 q][34]
  float* RHp = RWp + 544;                            // [16 q][34]

  // XCD-aware swizzle: 4 adjacent bx per XCD slot for KV L2 reuse
  int wgid = blockIdx.x;
  int xcd = wgid & 7, chnk = wgid >> 3;
  int bxlo = chnk & 3, rest = chnk >> 2;
  int c = xcd * 256 + rest;               // 0..2047
  int bx = (c & 3) * 4 + bxlo;
  int byy = (c >> 2) & 15;
  int bh = c >> 6;                        // 0..31
  int b = bh >> 3, hd = bh & 7;
  int blk = byy * 16 + bx;

  const bf16s* kvb = kv_ws + (((size_t)b * 134 + byy * 8) * 134 + bx * 8) * 512 + hd * 64;
  const bf16s* qg  = q_ws + ((size_t)bh * 256 + blk) * 2048;

  // --- per-lane operand fragments straight from global (L2-hot) ---
  bf16x8 aq = *(const bf16x8*)(qg + (wv * 16 + l15) * 32 + g * 8);   // B: q
  const int i_cl = (l15 < 14) ? l15 : 13;
  const bf16s* kbase = kvb + (size_t)i_cl * 68608 + g * 8;           // 134*512
  bf16x8 kf[14];
#pragma unroll
  for (int nt = 0; nt < 14; ++nt)
    kf[nt] = *(const bf16x8*)(kbase + nt * 512);                     // A: k rows
  bf16x8 wf[2], hf[2];
#pragma unroll
  for (int t16 = 0; t16 < 2; ++t16) {
    wf[t16] = *(const bf16x8*)(rel_b + (t16 * 16 + l15) * 32 + g * 8);
    hf[t16] = *(const bf16x8*)(rel_b + 1024 + (t16 * 16 + l15) * 32 + g * 8);
  }

  // --- cooperative vT staging: vT[d][j*16+i] = v[pixel(i,j)][d] ---
  for (int idx = t; idx < 784; idx += 256) {
    int pos = idx >> 2, ch = idx & 3;
    int i = pos / 14, j = pos - i * 14;
    bf16x8 v = *(const bf16x8*)(kvb + (size_t)(i * 134 + j) * 512 + 32 + ch * 8);
#pragma unroll
    for (int u = 0; u < 8; ++u) vT[(ch * 8 + u) * VSTRIDE + j * 16 + i] = v[u];
  }
  for (int idx = t; idx < 896; idx += 256) {  // zero pad cols i=14,15
    int d = idx / 28, r = idx - d * 28;
    vT[d * VSTRIDE + (r >> 1) * 16 + 14 + (r & 1)] = 0;
  }

  // --- QK^T (S^T): acc[nt] rows = keys nt*16+g*4+rg, col q ---
  f32x4 acc[14];
#pragma unroll
  for (int nt = 0; nt < 14; ++nt) acc[nt] = (f32x4){0.f, 0.f, 0.f, 0.f};
#pragma unroll
  for (int nt = 0; nt < 14; ++nt) acc[nt] = MFMA16(kf[nt], aq, acc[nt]);

  // --- rel logits: D[r][q] = q . rel[r]; fold LOG2E and -EXP_SHIFT here ---
  {
    f32x4 zz = (f32x4){0.f, 0.f, 0.f, 0.f};
#pragma unroll
    for (int t16 = 0; t16 < 2; ++t16) {
      f32x4 rw = MFMA16(wf[t16], aq, zz);
      f32x4 rh = MFMA16(hf[t16], aq, zz);
      float* wd = &RWp[l15 * 34 + t16 * 16 + g * 4];
      float* hd2 = &RHp[l15 * 34 + t16 * 16 + g * 4];
      *(float2*)wd       = make_float2(fmaf(rw[0], LOG2E, -EXP_SHIFT),
                                       fmaf(rw[1], LOG2E, -EXP_SHIFT));
      *(float2*)(wd + 2) = make_float2(fmaf(rw[2], LOG2E, -EXP_SHIFT),
                                       fmaf(rw[3], LOG2E, -EXP_SHIFT));
      *(float2*)hd2       = make_float2(rh[0] * LOG2E, rh[1] * LOG2E);
      *(float2*)(hd2 + 2) = make_float2(rh[2] * LOG2E, rh[3] * LOG2E);
    }
  }

  // --- softmax numerators (no normalize; fixed shift). jq=q&7, iq=q>>3 ---
  const int jq = l15 & 7;
  const int iq = wv * 2 + (l15 >> 3);
  const float* RWr = RWp + l15 * 34;
  const float* RHr = RHp + l15 * 34;
  const int ihb = 13 + g * 4 - iq;
  float h0 = RHr[ihb], h1 = RHr[ihb + 1], h2 = RHr[ihb + 2], h3 = RHr[ihb + 3];
  float sm = 0.f;
#pragma unroll
  for (int nt = 0; nt < 14; ++nt) {
    float w1 = RWr[13 + nt - jq];           // includes *LOG2E - EXP_SHIFT
    float e0 = exp2f(fmaf(acc[nt][0], SCLOG, w1 + h0));
    float e1 = exp2f(fmaf(acc[nt][1], SCLOG, w1 + h1));
    float e2 = exp2f(fmaf(acc[nt][2], SCLOG, w1 + h2));
    float e3 = exp2f(fmaf(acc[nt][3], SCLOG, w1 + h3));
    if (g == 3) { e2 = 0.f; e3 = 0.f; }   // key rows i=14,15 invalid
    sm += e0 + e1 + e2 + e3;
    acc[nt][0] = e0; acc[nt][1] = e1; acc[nt][2] = e2; acc[nt][3] = e3;
  }
  sm += __shfl_xor(sm, 16);
  sm += __shfl_xor(sm, 32);
  float rs = __builtin_amdgcn_rcpf(sm);

  __syncthreads();  // vT staged by all threads; P stays in registers

  // --- PV via 16x16x16 MFMA: O^T[d][q] = sum_nt Vt_nt * P_nt ---
  // B-frag: bpv[j] = P^T[key nt*16+g*4+j][q=l15] = acc[nt][j]  (layout match)
  // A-frag: a[j] = vT[d = l15 (+16)][key' = nt*16+g*4+j]
  f32x4 oa0 = (f32x4){0.f, 0.f, 0.f, 0.f};
  f32x4 oa1 = (f32x4){0.f, 0.f, 0.f, 0.f};
#pragma unroll
  for (int nt = 0; nt < 14; ++nt) {
    bf16x4 bpv;
    bpv[0] = f2b(acc[nt][0]); bpv[1] = f2b(acc[nt][1]);
    bpv[2] = f2b(acc[nt][2]); bpv[3] = f2b(acc[nt][3]);
    bf16x4 a0 = *(const bf16x4*)(vT + l15 * VSTRIDE + nt * 16 + g * 4);
    bf16x4 a1 = *(const bf16x4*)(vT + (16 + l15) * VSTRIDE + nt * 16 + g * 4);
    oa0 = pv_mfma(a0, bpv, oa0);
    oa1 = pv_mfma(a1, bpv, oa1);
  }

  // --- direct store: lane holds O[d = g*4+rg (+16)][q = wv*16+l15] ---
  {
    int py = wv * 2 + (l15 >> 3), px = l15 & 7;
    float* ob = outp + (((size_t)(b * 256 + hd * 32) * 128 + byy * 8 + py) * 128) +
                bx * 8 + px;
#pragma unroll
    for (int rg = 0; rg < 4; ++rg) {
      ob[(size_t)(g * 4 + rg) * 16384] = oa0[rg] * rs;
      ob[(size_t)(16 + g * 4 + rg) * 16384] = oa1[rg] * rs;
    }
  }
}

// ---------------------------------------------------------------------------
extern "C" void kernel_launch(void* const* d_in, const int* in_sizes, int n_in,
                              void* d_out, int out_size, void* d_ws, size_t ws_size,
                              hipStream_t stream) {
  (void)in_sizes; (void)n_in; (void)out_size; (void)ws_size;
  const float* x    = (const float*)d_in[0];
  const float* wq   = (const float*)d_in[1];
  const float* wkv  = (const float*)d_in[2];
  const float* hrel = (const float*)d_in[3];
  const float* wrel = (const float*)d_in[4];
  float* outp = (float*)d_out;

  bf16s* xT    = (bf16s*)d_ws;        // 16,777,216 elems
  bf16s* q_ws  = xT + 16777216;       // 16,777,216 elems
  bf16s* kv_ws = q_ws + 16777216;     // 36,773,888 elems
  bf16s* wq_b  = kv_ws + 36773888;    //     65,536
  bf16s* wkv_b = wq_b + 65536;        //    131,072
  bf16s* rel_b = wkv_b + 131072;      //      2,048

  hipLaunchKernelGGL(k_convert,    dim3(776),       dim3(256), 0, stream,
                     wq, wkv, hrel, wrel, wq_b, wkv_b, rel_b);
  hipLaunchKernelGGL(k_transpose,  dim3(4, 256, 4), dim3(256), 0, stream, x, xT);
  hipLaunchKernelGGL(k_zero_border, dim3(1572),     dim3(256), 0, stream, kv_ws);
  hipLaunchKernelGGL(k_qkv,        dim3(3072),      dim3(256), 0, stream,
                     wq_b, wkv_b, xT, q_ws, kv_ws);
  hipLaunchKernelGGL(k_attn,       dim3(8192),      dim3(256), 0, stream,
                     q_ws, kv_ws, rel_b, outp);
}